// Round 1
// 1024.891 us; speedup vs baseline: 1.5022x; 1.5022x over previous
//
// v9: k_stats rewritten — 1-wave blocks, register-pipelined LDS chain reads
// (ping-pong 16x float4 groups, loads issued one group ahead), lane-parallel
// square precompute for the variance pass. Chain FP order bit-identical to v8.
// All other kernels unchanged.
#include <hip/hip_runtime.h>

#define OFF_PSUM   0UL            // 134217728 B  f32 psum[b][1024][32][32]
#define OFF_ALPHA  134217728UL    // 1024 B
#define OFF_INV    134218752UL    // 4096 B
#define OFF_BT     134222848UL    // 4096 B   (total 134.23 MB, proven fits)

// ---------------- K0a: alpha — LDS-staged, exact sequential chain ----------------
__global__ __launch_bounds__(256) void k_alpha(const float* __restrict__ w,
                                               float* __restrict__ alpha) {
#pragma clang fp contract(off)
    __shared__ float buf[2304];
    int co = blockIdx.x, t = threadIdx.x;
    const float* p = w + (size_t)co * 2304;
    for (int i = t; i < 2304; i += 256) buf[i] = p[i];
    __syncthreads();
    if (t == 0) {
        float s = 0.f;
#pragma unroll 16
        for (int k = 0; k < 2304; ++k) s = s + fabsf(buf[k]);
        alpha[co] = s / 2304.0f;
    }
}

// ---------------- K0b: transposed +-alpha table wsaT[((g*9+tap)*64+ci)*256+co] ----------------
__global__ __launch_bounds__(256) void k_wsaT(const float* __restrict__ w,
                                              const float* __restrict__ alpha,
                                              float* __restrict__ wsaT) {
    int item = blockIdx.x * 256 + threadIdx.x;     // 589824 items
    int co = item & 255;
    int rest = item >> 8;                           // 0..2303
    int ci = rest & 63;
    int t9 = rest >> 6;                             // 0..35
    int tap = t9 % 9, g = t9 / 9;
    float av = alpha[co];
    float wv = w[((size_t)co * 256 + g * 64 + ci) * 9 + tap];
    wsaT[item] = (wv >= 0.f) ? av : -av;           // exact +-alpha, bit-same as r7/r8
}

// ---------------- K1: conv — ci-outer/co-inner, SGPR weights, 1 VALU per FMA ----------------
// block (b,g,band): 8 waves x 32 co; thread = 1 px; acc[32]; xv[64] register-resident
__global__ __launch_bounds__(512, 2) void k_conv(const float* __restrict__ x,
                                                 const float* __restrict__ wsaT,
                                                 float* __restrict__ psum) {
#pragma clang fp contract(off)
    __shared__ float xs[4][34][68];
    int bx = blockIdx.x;
    int band = bx & 15, g = (bx >> 4) & 3, b = bx >> 6;
    int t = threadIdx.x;

    const float* xg = x + (size_t)(b * 256 + g * 64) * 1024;
#pragma unroll
    for (int i = 0; i < 17; ++i) {                 // 17*512 = 8704 elements
        int idx = i * 512 + t;
        int ci = idx & 63, col = (idx >> 6) % 34, row = idx / 2176;
        int gr = band * 2 + row - 1, gc = col - 1;
        float v = (gr >= 0 && gr < 32 && gc >= 0 && gc < 32)
                    ? xg[(size_t)ci * 1024 + gr * 32 + gc] : 0.f;
        xs[row][col][ci] = v;
    }
    __syncthreads();

    int wid = t >> 6, lane = t & 63;
    int r = lane >> 5, m = lane & 31;
    int h = band * 2 + r;
    int cobase = __builtin_amdgcn_readfirstlane(wid * 32);   // wave-uniform

    float acc[32];
#pragma unroll
    for (int j = 0; j < 32; ++j) acc[j] = 0.f;

#pragma unroll 1
    for (int kh = 0; kh < 3; ++kh)
#pragma unroll 1
        for (int kw = 0; kw < 3; ++kw) {
            int tap = kh * 3 + kw;
            float xv[64];
            const float* bp = &xs[r + kh][m + kw][0];
#pragma unroll
            for (int q = 0; q < 16; ++q) {
                float4 v4 = *(const float4*)(bp + q * 4);
                xv[q * 4 + 0] = v4.x; xv[q * 4 + 1] = v4.y;
                xv[q * 4 + 2] = v4.z; xv[q * 4 + 3] = v4.w;
            }
            // wave-uniform weight row base for this (g,tap): wsaT[...][ci][co]
            const float* wt = wsaT + (((size_t)(g * 9 + tap) * 64) << 8) + cobase;
#pragma unroll
            for (int ci = 0; ci < 64; ++ci) {      // per-acc chain order preserved
                const float* wr = wt + (ci << 8);  // uniform -> s_load_dwordx16
#pragma unroll
                for (int j = 0; j < 32; ++j)
                    acc[j] = fmaf(xv[ci], wr[j], acc[j]);
            }
        }

#pragma unroll
    for (int j = 0; j < 32; ++j) {
        int co = cobase + j;
        psum[(((size_t)b * 1024 + g * 256 + co) * 32 + h) * 32 + m] = acc[j];
    }
}

// ---------------- K2 helper: bit-exact serial sum of 1024 floats from LDS ----------------
// Ping-pong register groups: 16x float4 (64 elems) loaded one group ahead of the
// dependent add chain. Same element order (0..1023) and same s = s + v sequence
// as v8 — only the load scheduling changed.
__device__ __forceinline__ float chain_sum_1024(const float* pb, float s) {
#pragma clang fp contract(off)
    float4 A[16], B[16];
#pragma unroll
    for (int u = 0; u < 16; ++u) A[u] = *(const float4*)(pb + u * 4);
#pragma unroll 1
    for (int g = 0; g < 8; ++g) {
        const float* p1 = pb + (2 * g + 1) * 64;
#pragma unroll
        for (int u = 0; u < 16; ++u) B[u] = *(const float4*)(p1 + u * 4);
#pragma unroll
        for (int u = 0; u < 16; ++u) {
            s = s + A[u].x; s = s + A[u].y; s = s + A[u].z; s = s + A[u].w;
        }
        const float* p2 = pb + (2 * g + 2) * 64;
        if (g < 7) {
#pragma unroll
            for (int u = 0; u < 16; ++u) A[u] = *(const float4*)(p2 + u * 4);
        }
#pragma unroll
        for (int u = 0; u < 16; ++u) {
            s = s + B[u].x; s = s + B[u].y; s = s + B[u].z; s = s + B[u].w;
        }
    }
    return s;
}

// ---------------- K2: BN stats — 1-wave block, pipelined chain, lane-parallel squares ----------------
__global__ __launch_bounds__(64, 1) void k_stats(const float* __restrict__ psum,
                                                 const float* __restrict__ gamma,
                                                 const float* __restrict__ beta,
                                                 float* __restrict__ invA,
                                                 float* __restrict__ btA) {
#pragma clang fp contract(off)
    __shared__ float buf[2][1024];
    __shared__ float res[1];
    int ch = blockIdx.x, t = threadIdx.x;
    const float* base = psum + (size_t)ch * 1024;

    // ---- pass 1: mean (chain order identical to v8) ----
    float4 pre[4];
#pragma unroll
    for (int r = 0; r < 4; ++r) pre[r] = *(const float4*)(base + r * 256 + t * 4);
#pragma unroll
    for (int r = 0; r < 4; ++r) *(float4*)&buf[0][r * 256 + t * 4] = pre[r];
    __syncthreads();

    float s = 0.f;
    for (int b = 0; b < 32; ++b) {
        if (b + 1 < 32) {
            const float* nb = base + (size_t)(b + 1) * 1048576;
#pragma unroll
            for (int r = 0; r < 4; ++r) pre[r] = *(const float4*)(nb + r * 256 + t * 4);
        }
        if (t == 0) s = chain_sum_1024(buf[b & 1], s);
        __syncthreads();
        if (b + 1 < 32) {
#pragma unroll
            for (int r = 0; r < 4; ++r) *(float4*)&buf[(b + 1) & 1][r * 256 + t * 4] = pre[r];
        }
        __syncthreads();
    }
    if (t == 0) res[0] = s / 32768.0f;
    __syncthreads();
    float mean = res[0];

    // ---- pass 2: var. d = p - mean; q = d*d computed lane-parallel (bit-identical
    // f32 ops, order-independent); chain thread adds q in exact element order. ----
#pragma unroll
    for (int r = 0; r < 4; ++r) pre[r] = *(const float4*)(base + r * 256 + t * 4);
    {
        float4 sq[4];
#pragma unroll
        for (int r = 0; r < 4; ++r) {
            float d0 = pre[r].x - mean; sq[r].x = d0 * d0;
            float d1 = pre[r].y - mean; sq[r].y = d1 * d1;
            float d2 = pre[r].z - mean; sq[r].z = d2 * d2;
            float d3 = pre[r].w - mean; sq[r].w = d3 * d3;
        }
#pragma unroll
        for (int r = 0; r < 4; ++r) *(float4*)&buf[0][r * 256 + t * 4] = sq[r];
    }
    __syncthreads();

    float v = 0.f;
    for (int b = 0; b < 32; ++b) {
        if (b + 1 < 32) {
            const float* nb = base + (size_t)(b + 1) * 1048576;
#pragma unroll
            for (int r = 0; r < 4; ++r) pre[r] = *(const float4*)(nb + r * 256 + t * 4);
        }
        if (t == 0) v = chain_sum_1024(buf[b & 1], v);
        __syncthreads();
        if (b + 1 < 32) {
            float4 sq[4];
#pragma unroll
            for (int r = 0; r < 4; ++r) {
                float d0 = pre[r].x - mean; sq[r].x = d0 * d0;
                float d1 = pre[r].y - mean; sq[r].y = d1 * d1;
                float d2 = pre[r].z - mean; sq[r].z = d2 * d2;
                float d3 = pre[r].w - mean; sq[r].w = d3 * d3;
            }
#pragma unroll
            for (int r = 0; r < 4; ++r) *(float4*)&buf[(b + 1) & 1][r * 256 + t * 4] = sq[r];
        }
        __syncthreads();
    }
    if (t == 0) {
        float var = v / 32768.0f;
        float sq = sqrtf(var + 1e-5f);
        float inv = 1.0f / sq;
        inv = inv * gamma[ch];
        float mb = mean * inv;
        invA[ch] = inv;
        btA[ch] = beta[ch] - mb;
    }
}

// ---------------- K3: BN apply + sign + merge + literal qrelu (unchanged, passed) ----------------
__global__ __launch_bounds__(256) void k_apply(const float* __restrict__ psum,
                                               const float* __restrict__ invA,
                                               const float* __restrict__ btA,
                                               float* __restrict__ out) {
#pragma clang fp contract(off)
    int idx = blockIdx.x * 256 + threadIdx.x;
    int w4 = (idx & 7) * 4;
    int hh = (idx >> 3) & 31;
    int co = (idx >> 8) & 255;
    int b  = idx >> 16;

    float s0 = 0.f, s1 = 0.f, s2 = 0.f, s3 = 0.f;
    for (int g = 0; g < 4; ++g) {
        int ch = g * 256 + co;
        const float4 p = *(const float4*)(psum + (((size_t)b * 1024 + ch) * 32 + hh) * 32 + w4);
        float iv = invA[ch], bt = btA[ch];
        float y0 = p.x * iv; y0 = y0 + bt;
        float y1 = p.y * iv; y1 = y1 + bt;
        float y2 = p.z * iv; y2 = y2 + bt;
        float y3 = p.w * iv; y3 = y3 + bt;
        s0 = s0 + ((y0 >= 0.f) ? 1.f : -1.f);
        s1 = s1 + ((y1 >= 0.f) ? 1.f : -1.f);
        s2 = s2 + ((y2 >= 0.f) ? 1.f : -1.f);
        s3 = s3 + ((y3 >= 0.f) ? 1.f : -1.f);
    }
    float4 q;
    {
        float u, rr, qq;
        u = s0 * 0.25f; u = fminf(fmaxf(u, 0.f), 1.f); rr = rintf(u * 15.f); qq = rr / 15.f; q.x = qq * 4.f;
        u = s1 * 0.25f; u = fminf(fmaxf(u, 0.f), 1.f); rr = rintf(u * 15.f); qq = rr / 15.f; q.y = qq * 4.f;
        u = s2 * 0.25f; u = fminf(fmaxf(u, 0.f), 1.f); rr = rintf(u * 15.f); qq = rr / 15.f; q.z = qq * 4.f;
        u = s3 * 0.25f; u = fminf(fmaxf(u, 0.f), 1.f); rr = rintf(u * 15.f); qq = rr / 15.f; q.w = qq * 4.f;
    }
    *(float4*)(out + (((size_t)b * 256 + co) * 32 + hh) * 32 + w4) = q;
}

extern "C" void kernel_launch(void* const* d_in, const int* in_sizes, int n_in,
                              void* d_out, int out_size, void* d_ws, size_t ws_size,
                              hipStream_t stream) {
    (void)in_sizes; (void)n_in; (void)out_size; (void)ws_size;
    const float* x     = (const float*)d_in[0];
    const float* w     = (const float*)d_in[1];
    const float* gamma = (const float*)d_in[2];
    const float* beta  = (const float*)d_in[3];
    float* out = (float*)d_out;
    char* ws = (char*)d_ws;
    float* psum  = (float*)(ws + OFF_PSUM);
    float* alpha = (float*)(ws + OFF_ALPHA);
    float* invA  = (float*)(ws + OFF_INV);
    float* btA   = (float*)(ws + OFF_BT);
    float* wsaT  = out;                 // 2.36 MB scratch in d_out; k_apply overwrites later

    hipLaunchKernelGGL(k_alpha, dim3(256),  dim3(256), 0, stream, w, alpha);
    hipLaunchKernelGGL(k_wsaT,  dim3(2304), dim3(256), 0, stream, w, alpha, wsaT);
    hipLaunchKernelGGL(k_conv,  dim3(2048), dim3(512), 0, stream, x, wsaT, psum);
    hipLaunchKernelGGL(k_stats, dim3(1024), dim3(64),  0, stream, psum, gamma, beta, invA, btA);
    hipLaunchKernelGGL(k_apply, dim3(8192), dim3(256), 0, stream, psum, invA, btA, out);
}

// Round 2
// 905.478 us; speedup vs baseline: 1.7003x; 1.1319x over previous
//
// v10: k_conv — 2 px per thread (rows h, h+2 of a 4-row band) sharing each
// SGPR weight row: 64 FMAs per 128 B weight fetch (was 32), halving the
// scalar-load rate the chain must hide. ci chunked by 16 to keep VGPR<=128
// (launch_bounds(512,4)); per-acc chain order (kh,kw,ci) bit-identical.
// k_stats (v9 pipelined 1-wave), k_alpha, k_wsaT, k_apply unchanged.
#include <hip/hip_runtime.h>

#define OFF_PSUM   0UL            // 134217728 B  f32 psum[b][1024][32][32]
#define OFF_ALPHA  134217728UL    // 1024 B
#define OFF_INV    134218752UL    // 4096 B
#define OFF_BT     134222848UL    // 4096 B   (total 134.23 MB, proven fits)

// ---------------- K0a: alpha — LDS-staged, exact sequential chain ----------------
__global__ __launch_bounds__(256) void k_alpha(const float* __restrict__ w,
                                               float* __restrict__ alpha) {
#pragma clang fp contract(off)
    __shared__ float buf[2304];
    int co = blockIdx.x, t = threadIdx.x;
    const float* p = w + (size_t)co * 2304;
    for (int i = t; i < 2304; i += 256) buf[i] = p[i];
    __syncthreads();
    if (t == 0) {
        float s = 0.f;
#pragma unroll 16
        for (int k = 0; k < 2304; ++k) s = s + fabsf(buf[k]);
        alpha[co] = s / 2304.0f;
    }
}

// ---------------- K0b: transposed +-alpha table wsaT[((g*9+tap)*64+ci)*256+co] ----------------
__global__ __launch_bounds__(256) void k_wsaT(const float* __restrict__ w,
                                              const float* __restrict__ alpha,
                                              float* __restrict__ wsaT) {
    int item = blockIdx.x * 256 + threadIdx.x;     // 589824 items
    int co = item & 255;
    int rest = item >> 8;                           // 0..2303
    int ci = rest & 63;
    int t9 = rest >> 6;                             // 0..35
    int tap = t9 % 9, g = t9 / 9;
    float av = alpha[co];
    float wv = w[((size_t)co * 256 + g * 64 + ci) * 9 + tap];
    wsaT[item] = (wv >= 0.f) ? av : -av;           // exact +-alpha
}

// ---------------- K1: conv — 2 px/thread, SGPR weights, 64 FMA per weight row ----------------
// block (b,g,band4): 8 waves x 32 co; thread = px (h,m) and (h+2,m); acc0/acc1[32]
__global__ __launch_bounds__(512, 4) void k_conv(const float* __restrict__ x,
                                                 const float* __restrict__ wsaT,
                                                 float* __restrict__ psum) {
#pragma clang fp contract(off)
    __shared__ float xs[6][34][68];
    int bx = blockIdx.x;
    int band = bx & 7, g = (bx >> 3) & 3, b = bx >> 5;   // 1024 blocks
    int t = threadIdx.x;

    const float* xg = x + (size_t)(b * 256 + g * 64) * 1024;
#pragma unroll 1
    for (int i = 0; i < 26; ++i) {                 // 6*34*64 = 13056 elements
        int idx = i * 512 + t;
        if (idx < 13056) {
            int ci = idx & 63, col = (idx >> 6) % 34, row = idx / 2176;
            int gr = band * 4 + row - 1, gc = col - 1;
            float v = (gr >= 0 && gr < 32 && gc >= 0 && gc < 32)
                        ? xg[(size_t)ci * 1024 + gr * 32 + gc] : 0.f;
            xs[row][col][ci] = v;
        }
    }
    __syncthreads();

    int wid = t >> 6, lane = t & 63;
    int r = lane >> 5, m = lane & 31;
    int h0 = band * 4 + r;                          // second px at h0+2
    int cobase = __builtin_amdgcn_readfirstlane(wid * 32);   // wave-uniform

    float acc0[32], acc1[32];
#pragma unroll
    for (int j = 0; j < 32; ++j) { acc0[j] = 0.f; acc1[j] = 0.f; }

#pragma unroll 1
    for (int kh = 0; kh < 3; ++kh)
#pragma unroll 1
        for (int kw = 0; kw < 3; ++kw) {
            int tap = kh * 3 + kw;
            const float* bp0 = &xs[r + kh][m + kw][0];
            const float* bp1 = &xs[r + 2 + kh][m + kw][0];
            // wave-uniform weight row base for this (g,tap): wsaT[...][ci][co]
            const float* wt = wsaT + (((size_t)(g * 9 + tap) * 64) << 8) + cobase;
#pragma unroll
            for (int c = 0; c < 4; ++c) {           // ci chunks of 16
                float xv0[16], xv1[16];
#pragma unroll
                for (int q = 0; q < 4; ++q) {
                    float4 a = *(const float4*)(bp0 + c * 16 + q * 4);
                    xv0[q * 4 + 0] = a.x; xv0[q * 4 + 1] = a.y;
                    xv0[q * 4 + 2] = a.z; xv0[q * 4 + 3] = a.w;
                    float4 d = *(const float4*)(bp1 + c * 16 + q * 4);
                    xv1[q * 4 + 0] = d.x; xv1[q * 4 + 1] = d.y;
                    xv1[q * 4 + 2] = d.z; xv1[q * 4 + 3] = d.w;
                }
#pragma unroll
                for (int ci = 0; ci < 16; ++ci) {   // per-acc chain order preserved
                    const float* wr = wt + ((c * 16 + ci) << 8);  // uniform -> s_load
#pragma unroll
                    for (int j = 0; j < 32; ++j)
                        acc0[j] = fmaf(xv0[ci], wr[j], acc0[j]);
#pragma unroll
                    for (int j = 0; j < 32; ++j)
                        acc1[j] = fmaf(xv1[ci], wr[j], acc1[j]);
                }
            }
        }

#pragma unroll
    for (int j = 0; j < 32; ++j) {
        int co = cobase + j;
        size_t rowo = ((size_t)b * 1024 + g * 256 + co) * 32;
        psum[(rowo + h0) * 32 + m]     = acc0[j];
        psum[(rowo + h0 + 2) * 32 + m] = acc1[j];
    }
}

// ---------------- K2 helper: bit-exact serial sum of 1024 floats from LDS ----------------
__device__ __forceinline__ float chain_sum_1024(const float* pb, float s) {
#pragma clang fp contract(off)
    float4 A[16], B[16];
#pragma unroll
    for (int u = 0; u < 16; ++u) A[u] = *(const float4*)(pb + u * 4);
#pragma unroll 1
    for (int g = 0; g < 8; ++g) {
        const float* p1 = pb + (2 * g + 1) * 64;
#pragma unroll
        for (int u = 0; u < 16; ++u) B[u] = *(const float4*)(p1 + u * 4);
#pragma unroll
        for (int u = 0; u < 16; ++u) {
            s = s + A[u].x; s = s + A[u].y; s = s + A[u].z; s = s + A[u].w;
        }
        const float* p2 = pb + (2 * g + 2) * 64;
        if (g < 7) {
#pragma unroll
            for (int u = 0; u < 16; ++u) A[u] = *(const float4*)(p2 + u * 4);
        }
#pragma unroll
        for (int u = 0; u < 16; ++u) {
            s = s + B[u].x; s = s + B[u].y; s = s + B[u].z; s = s + B[u].w;
        }
    }
    return s;
}

// ---------------- K2: BN stats — 1-wave block, pipelined chain, lane-parallel squares ----------------
__global__ __launch_bounds__(64, 1) void k_stats(const float* __restrict__ psum,
                                                 const float* __restrict__ gamma,
                                                 const float* __restrict__ beta,
                                                 float* __restrict__ invA,
                                                 float* __restrict__ btA) {
#pragma clang fp contract(off)
    __shared__ float buf[2][1024];
    __shared__ float res[1];
    int ch = blockIdx.x, t = threadIdx.x;
    const float* base = psum + (size_t)ch * 1024;

    // ---- pass 1: mean (chain order identical to v8) ----
    float4 pre[4];
#pragma unroll
    for (int r = 0; r < 4; ++r) pre[r] = *(const float4*)(base + r * 256 + t * 4);
#pragma unroll
    for (int r = 0; r < 4; ++r) *(float4*)&buf[0][r * 256 + t * 4] = pre[r];
    __syncthreads();

    float s = 0.f;
    for (int b = 0; b < 32; ++b) {
        if (b + 1 < 32) {
            const float* nb = base + (size_t)(b + 1) * 1048576;
#pragma unroll
            for (int r = 0; r < 4; ++r) pre[r] = *(const float4*)(nb + r * 256 + t * 4);
        }
        if (t == 0) s = chain_sum_1024(buf[b & 1], s);
        __syncthreads();
        if (b + 1 < 32) {
#pragma unroll
            for (int r = 0; r < 4; ++r) *(float4*)&buf[(b + 1) & 1][r * 256 + t * 4] = pre[r];
        }
        __syncthreads();
    }
    if (t == 0) res[0] = s / 32768.0f;
    __syncthreads();
    float mean = res[0];

    // ---- pass 2: var. d = p - mean; q = d*d computed lane-parallel (bit-identical
    // f32 ops, order-independent); chain thread adds q in exact element order. ----
#pragma unroll
    for (int r = 0; r < 4; ++r) pre[r] = *(const float4*)(base + r * 256 + t * 4);
    {
        float4 sq[4];
#pragma unroll
        for (int r = 0; r < 4; ++r) {
            float d0 = pre[r].x - mean; sq[r].x = d0 * d0;
            float d1 = pre[r].y - mean; sq[r].y = d1 * d1;
            float d2 = pre[r].z - mean; sq[r].z = d2 * d2;
            float d3 = pre[r].w - mean; sq[r].w = d3 * d3;
        }
#pragma unroll
        for (int r = 0; r < 4; ++r) *(float4*)&buf[0][r * 256 + t * 4] = sq[r];
    }
    __syncthreads();

    float v = 0.f;
    for (int b = 0; b < 32; ++b) {
        if (b + 1 < 32) {
            const float* nb = base + (size_t)(b + 1) * 1048576;
#pragma unroll
            for (int r = 0; r < 4; ++r) pre[r] = *(const float4*)(nb + r * 256 + t * 4);
        }
        if (t == 0) v = chain_sum_1024(buf[b & 1], v);
        __syncthreads();
        if (b + 1 < 32) {
            float4 sq[4];
#pragma unroll
            for (int r = 0; r < 4; ++r) {
                float d0 = pre[r].x - mean; sq[r].x = d0 * d0;
                float d1 = pre[r].y - mean; sq[r].y = d1 * d1;
                float d2 = pre[r].z - mean; sq[r].z = d2 * d2;
                float d3 = pre[r].w - mean; sq[r].w = d3 * d3;
            }
#pragma unroll
            for (int r = 0; r < 4; ++r) *(float4*)&buf[(b + 1) & 1][r * 256 + t * 4] = sq[r];
        }
        __syncthreads();
    }
    if (t == 0) {
        float var = v / 32768.0f;
        float sq = sqrtf(var + 1e-5f);
        float inv = 1.0f / sq;
        inv = inv * gamma[ch];
        float mb = mean * inv;
        invA[ch] = inv;
        btA[ch] = beta[ch] - mb;
    }
}

// ---------------- K3: BN apply + sign + merge + literal qrelu (unchanged, passed) ----------------
__global__ __launch_bounds__(256) void k_apply(const float* __restrict__ psum,
                                               const float* __restrict__ invA,
                                               const float* __restrict__ btA,
                                               float* __restrict__ out) {
#pragma clang fp contract(off)
    int idx = blockIdx.x * 256 + threadIdx.x;
    int w4 = (idx & 7) * 4;
    int hh = (idx >> 3) & 31;
    int co = (idx >> 8) & 255;
    int b  = idx >> 16;

    float s0 = 0.f, s1 = 0.f, s2 = 0.f, s3 = 0.f;
    for (int g = 0; g < 4; ++g) {
        int ch = g * 256 + co;
        const float4 p = *(const float4*)(psum + (((size_t)b * 1024 + ch) * 32 + hh) * 32 + w4);
        float iv = invA[ch], bt = btA[ch];
        float y0 = p.x * iv; y0 = y0 + bt;
        float y1 = p.y * iv; y1 = y1 + bt;
        float y2 = p.z * iv; y2 = y2 + bt;
        float y3 = p.w * iv; y3 = y3 + bt;
        s0 = s0 + ((y0 >= 0.f) ? 1.f : -1.f);
        s1 = s1 + ((y1 >= 0.f) ? 1.f : -1.f);
        s2 = s2 + ((y2 >= 0.f) ? 1.f : -1.f);
        s3 = s3 + ((y3 >= 0.f) ? 1.f : -1.f);
    }
    float4 q;
    {
        float u, rr, qq;
        u = s0 * 0.25f; u = fminf(fmaxf(u, 0.f), 1.f); rr = rintf(u * 15.f); qq = rr / 15.f; q.x = qq * 4.f;
        u = s1 * 0.25f; u = fminf(fmaxf(u, 0.f), 1.f); rr = rintf(u * 15.f); qq = rr / 15.f; q.y = qq * 4.f;
        u = s2 * 0.25f; u = fminf(fmaxf(u, 0.f), 1.f); rr = rintf(u * 15.f); qq = rr / 15.f; q.z = qq * 4.f;
        u = s3 * 0.25f; u = fminf(fmaxf(u, 0.f), 1.f); rr = rintf(u * 15.f); qq = rr / 15.f; q.w = qq * 4.f;
    }
    *(float4*)(out + (((size_t)b * 256 + co) * 32 + hh) * 32 + w4) = q;
}

extern "C" void kernel_launch(void* const* d_in, const int* in_sizes, int n_in,
                              void* d_out, int out_size, void* d_ws, size_t ws_size,
                              hipStream_t stream) {
    (void)in_sizes; (void)n_in; (void)out_size; (void)ws_size;
    const float* x     = (const float*)d_in[0];
    const float* w     = (const float*)d_in[1];
    const float* gamma = (const float*)d_in[2];
    const float* beta  = (const float*)d_in[3];
    float* out = (float*)d_out;
    char* ws = (char*)d_ws;
    float* psum  = (float*)(ws + OFF_PSUM);
    float* alpha = (float*)(ws + OFF_ALPHA);
    float* invA  = (float*)(ws + OFF_INV);
    float* btA   = (float*)(ws + OFF_BT);
    float* wsaT  = out;                 // 2.36 MB scratch in d_out; k_apply overwrites later

    hipLaunchKernelGGL(k_alpha, dim3(256),  dim3(256), 0, stream, w, alpha);
    hipLaunchKernelGGL(k_wsaT,  dim3(2304), dim3(256), 0, stream, w, alpha, wsaT);
    hipLaunchKernelGGL(k_conv,  dim3(1024), dim3(512), 0, stream, x, wsaT, psum);
    hipLaunchKernelGGL(k_stats, dim3(1024), dim3(64),  0, stream, psum, gamma, beta, invA, btA);
    hipLaunchKernelGGL(k_apply, dim3(8192), dim3(256), 0, stream, psum, invA, btA, out);
}